// Round 11
// baseline (924.231 us; speedup 1.0000x reference)
//
#include <hip/hip_runtime.h>
#include <hip/hip_bf16.h>
#include <math.h>

#define B_  256
#define T_  40
#define IN_ 2048
#define E_  512
#define H_  1024
#define V_  5000
#define G4_ 4096   // 4*H

typedef __bf16 bf16x8 __attribute__((ext_vector_type(8)));
typedef float  f32x4  __attribute__((ext_vector_type(4)));
typedef unsigned int u32x4 __attribute__((ext_vector_type(4)));

__device__ __forceinline__ float sigm_f(float x) { return 1.0f / (1.0f + __expf(-x)); }
__device__ __forceinline__ float tanh_f(float x) { return 1.0f - 2.0f / (1.0f + __expf(2.0f * x)); }

__device__ __forceinline__ unsigned short f2b(float x) {
    __hip_bfloat16 h = __float2bfloat16(x);
    return *reinterpret_cast<unsigned short*>(&h);
}
__device__ __forceinline__ float b2f(unsigned short u) {
    unsigned int v = (unsigned int)u << 16;
    return __builtin_bit_cast(float, v);
}

#define GLOAD_LDS(g, l) __builtin_amdgcn_global_load_lds(                     \
    (const __attribute__((address_space(1))) unsigned int*)(g),               \
    (__attribute__((address_space(3))) unsigned int*)(l), 16, 0, 0)

// normal (L2-cached) 16B load, manual vmcnt accounting via VM_WAIT
__device__ __forceinline__ void l2_load16(u32x4* dst, const unsigned short* p) {
    asm volatile("global_load_dwordx4 %0, %1, off" : "=v"(*dst) : "v"(p));
}
// LLC-coherent (cross-XCD) stores + poll
__device__ __forceinline__ void llc_store16(unsigned short* p, u32x4 v) {
    asm volatile("global_store_dwordx4 %0, %1, off sc0 sc1" :: "v"(p), "v"(v) : "memory");
}
__device__ __forceinline__ void llc_store4(unsigned int* p, unsigned int v) {
    asm volatile("global_store_dword %0, %1, off sc0 sc1" :: "v"(p), "v"(v) : "memory");
}
// poll load: waitcnt INSIDE the asm (compiler doesn't track asm loads)
__device__ __forceinline__ unsigned int llc_load4_wait(const unsigned int* p) {
    unsigned int v;
    asm volatile("global_load_dword %0, %1, off sc0 sc1\n\ts_waitcnt vmcnt(0)"
                 : "=v"(v) : "v"(p) : "memory");
    return v;
}
#define VM_WAIT(n) do {                                                       \
    asm volatile("s_waitcnt vmcnt(" #n ")" ::: "memory");                     \
    __builtin_amdgcn_sched_barrier(0);                                        \
} while (0)

// ---------------------------------------------------------------------------
// MEGA KERNEL: spatially-partitioned recurrence + logits GEMM.
// Grid 3328 x 256 thr, dynamic LDS 137216 B -> exactly 1 block/CU.
//
// Blocks 0..127: persistent LSTM recurrence on 128 CUs.
//   WG (rg = bid>>6 in {0,1}, hb = bid&63): batch rows rg*128..+128,
//   h-cols hb*16..+16. W_hh slice [64 gate-rows x 1024] bf16 LDS (128 KB,
//   XOR-swizzled). Each wave: 2 row-sets x 16 rows x 16 hc x 4 gates,
//   c-state in VGPRs, cell per-lane. h blocked [64 kblk][256 row][16],
//   per-WG tile = contiguous 4 KB, stored by wave 0 (256 x 16B sc0sc1).
//   Flags: [(T+1)][128], entry rg*64+hb; consumers 64-lane poll + __all.
//   gates: bf16 quads EMBEDDED IN d_out: gates[t][b] = 8 KB at us-offset
//   (b*40+t)*10000 (out row b*40+t holds 20 KB) -> clobbered only by the
//   logits tile for t, which starts strictly after step t completes.
//
// Blocks 128..3327: logits tiles C[10240,5000] = hs @ Wout^T + b_out.
//   g = bid-128; m = g/40 (t = m>>1, rg = m&1), n = g%40. Tile waits on
//   flag group (slot t+1, rg) then runs a 2-phase 128x128 GEMM (32 KB of
//   LDS). C row r = t*256+b scatters to out[(b*40+t)*5000 + col].
//   t ascends with bid -> waiting blocks are next-to-ready. Recur never
//   waits on GEMM -> no deadlock. After recur exits, its CUs drain tiles.
// ---------------------------------------------------------------------------
__global__ __launch_bounds__(256) void mega(
    unsigned short* __restrict__ hs,          // slots 1..40, each 262144 elems
    const unsigned short* __restrict__ Whh,   // [4096,1024] bf16
    const unsigned short* __restrict__ gates, // us view of d_out (see above)
    unsigned int* __restrict__ flags,         // [(T+1)*128], zeroed
    const unsigned short* __restrict__ Wout,  // [5120,1024] bf16
    const float* __restrict__ b_out,          // [5000]
    float* __restrict__ out)                  // [10240,5000] f32
{
    extern __shared__ unsigned short lds[];
    const int tid = threadIdx.x;
    const int bid = blockIdx.x;
    const size_t SLOT = 262144;

    if (bid < 128) {
        // =================== RECURRENCE PATH ===================
        const int rg = bid >> 6, hb = bid & 63;
        const int w = tid >> 6, lane = tid & 63;
        const int r16 = lane & 15, g4 = lane >> 4;
        const int sw7 = r16 & 7;
        unsigned short* hstage = lds + 65536;   // [128][24] us

        // ---- stage W_hh slice into LDS once (wave w = gate q) ----
        {
            const int q = w;
            for (int r = 0; r < 16; ++r) {
                const int gg = q * 16 + r;
                const unsigned short* rowsrc =
                    Whh + (size_t)(q * 1024 + hb * 16 + r) * 1024;
                #pragma unroll
                for (int half = 0; half < 2; ++half) {
                    int gran = (half * 64 + lane) ^ (gg & 7);
                    GLOAD_LDS(rowsrc + gran * 8, &lds[gg * 1024 + half * 512]);
                }
            }
        }
        asm volatile("s_waitcnt vmcnt(0)" ::: "memory");
        __syncthreads();

        int qbase[4];
        #pragma unroll
        for (int q = 0; q < 4; ++q) qbase[q] = (q * 16 + r16) << 11;

        size_t abase[2];
        int orow0[2];
        #pragma unroll
        for (int s = 0; s < 2; ++s) {
            int ar = rg * 128 + s * 64 + w * 16 + r16;
            abase[s] = ((size_t)ar << 4) + ((g4 >> 1) << 12) + ((g4 & 1) << 3);
            orow0[s] = rg * 128 + s * 64 + w * 16 + g4 * 4;
        }
        const int hc = hb * 16 + r16;
        const int lrow0 = w * 16 + g4 * 4;

        // gates us-base for (row, t=0): row*40*10000 + hc*4; +j rows: +400000
        size_t gb[2];
        #pragma unroll
        for (int s = 0; s < 2; ++s)
            gb[s] = (size_t)orow0[s] * 400000 + ((size_t)hc << 2);

        float cc[2][4];
        ushort4 gqc[2][4], gqn[2][4];
        #pragma unroll
        for (int s = 0; s < 2; ++s)
            #pragma unroll
            for (int j = 0; j < 4; ++j)
                gqc[s][j] = *(const ushort4*)(gates + gb[s] + (size_t)j * 400000);

        #define R_STORE(T1)                                                   \
        {                                                                     \
            __syncthreads();                                                  \
            if (w == 0) {                                                     \
                unsigned short* dst0 = hs + (size_t)(T1) * SLOT +             \
                    (((size_t)hb * 256 + rg * 128) << 4);                     \
                _Pragma("unroll")                                             \
                for (int s2 = 0; s2 < 4; ++s2) {                              \
                    int idx = s2 * 64 + lane;                                 \
                    u32x4 v = *(const u32x4*)&hstage[(idx >> 1) * 24 +        \
                                                     (idx & 1) * 8];          \
                    llc_store16(dst0 + (size_t)idx * 8, v);                   \
                }                                                             \
                asm volatile("s_waitcnt vmcnt(0)" ::: "memory");              \
                if (lane == 0)                                                \
                    llc_store4(flags + (T1) * 128 + rg * 64 + hb, 1u);        \
            }                                                                 \
        }

        // ---- step 0: h0 = 0 -> gates only; prefetch step-1 gates ----
        {
            #pragma unroll
            for (int s = 0; s < 2; ++s)
                #pragma unroll
                for (int j = 0; j < 4; ++j)
                    gqn[s][j] = *(const ushort4*)(gates + gb[s] +
                                                  (size_t)j * 400000 + 10000);
            #pragma unroll
            for (int s = 0; s < 2; ++s)
                #pragma unroll
                for (int j = 0; j < 4; ++j) {
                    float gi = b2f(gqc[s][j].x);
                    float gg2 = b2f(gqc[s][j].z);
                    float go = b2f(gqc[s][j].w);
                    float c2 = sigm_f(gi) * tanh_f(gg2);
                    cc[s][j] = c2;
                    hstage[(s * 64 + lrow0 + j) * 24 + r16] =
                        f2b(sigm_f(go) * tanh_f(c2));
                }
            R_STORE(1)
            #pragma unroll
            for (int s = 0; s < 2; ++s)
                #pragma unroll
                for (int j = 0; j < 4; ++j) gqc[s][j] = gqn[s][j];
        }

        #define DO_CHUNK(S, BUF, KSB)                                         \
            _Pragma("unroll")                                                 \
            for (int u = 0; u < 8; ++u) {                                     \
                bf16x8 a8 = __builtin_bit_cast(bf16x8, BUF[u]);               \
                _Pragma("unroll")                                             \
                for (int q = 0; q < 4; ++q) {                                 \
                    int boff = qbase[q] +                                     \
                        (((((KSB) + u) * 4 + g4) ^ sw7) << 4);                \
                    bf16x8 b8 = *(const bf16x8*)((const char*)lds + boff);    \
                    acc[S][q] = __builtin_amdgcn_mfma_f32_16x16x32_bf16(      \
                        a8, b8, acc[S][q], 0, 0, 0);                          \
                }                                                             \
            }

        // ---- steps 1..39 ----
        for (int t = 1; t < T_; ++t) {
            {
                const unsigned int* fp = flags + t * 128 + rg * 64 + lane;
                for (;;) {
                    unsigned int fv = llc_load4_wait(fp);
                    if (__all(fv == 1u)) break;
                    __builtin_amdgcn_s_sleep(1);
                }
            }
            __builtin_amdgcn_sched_barrier(0);

            f32x4 acc[2][4] = {};
            #pragma unroll
            for (int s = 0; s < 2; ++s) {
                const unsigned short* hp = hs + (size_t)t * SLOT + abase[s];
                u32x4 a0[8], a1[8];
                #pragma unroll
                for (int u = 0; u < 8; ++u)
                    l2_load16(&a0[u], hp + (size_t)u * 8192);
                #pragma unroll
                for (int u = 0; u < 8; ++u)
                    l2_load16(&a1[u], hp + (size_t)(8 + u) * 8192);
                VM_WAIT(8);
                DO_CHUNK(s, a0, 0)
                #pragma unroll
                for (int u = 0; u < 8; ++u)
                    l2_load16(&a0[u], hp + (size_t)(16 + u) * 8192);
                VM_WAIT(8);
                DO_CHUNK(s, a1, 8)
                #pragma unroll
                for (int u = 0; u < 8; ++u)
                    l2_load16(&a1[u], hp + (size_t)(24 + u) * 8192);
                VM_WAIT(8);
                DO_CHUNK(s, a0, 16)
                VM_WAIT(0);
                DO_CHUNK(s, a1, 24)
            }

            if (t + 1 < T_) {
                #pragma unroll
                for (int s = 0; s < 2; ++s)
                    #pragma unroll
                    for (int j = 0; j < 4; ++j)
                        gqn[s][j] = *(const ushort4*)(gates + gb[s] +
                            (size_t)j * 400000 + (size_t)(t + 1) * 10000);
            }

            #pragma unroll
            for (int s = 0; s < 2; ++s)
                #pragma unroll
                for (int j = 0; j < 4; ++j) {
                    float gi = acc[s][0][j] + b2f(gqc[s][j].x);
                    float gf = acc[s][1][j] + b2f(gqc[s][j].y);
                    float gg2 = acc[s][2][j] + b2f(gqc[s][j].z);
                    float go = acc[s][3][j] + b2f(gqc[s][j].w);
                    float c2 = sigm_f(gf) * cc[s][j] + sigm_f(gi) * tanh_f(gg2);
                    cc[s][j] = c2;
                    hstage[(s * 64 + lrow0 + j) * 24 + r16] =
                        f2b(sigm_f(go) * tanh_f(c2));
                }
            R_STORE(t + 1)
            #pragma unroll
            for (int s = 0; s < 2; ++s)
                #pragma unroll
                for (int j = 0; j < 4; ++j) gqc[s][j] = gqn[s][j];
        }
        #undef DO_CHUNK
        #undef R_STORE
        return;
    }

    // =================== LOGITS GEMM PATH ===================
    const int g = bid - 128;
    const int m = g / 40;
    const int n = g - m * 40;
    const int t = m >> 1, rg = m & 1;
    const int wave = tid >> 6, lane = tid & 63;

    // wait for hs slot t+1, row group rg
    {
        const unsigned int* fp = flags + (t + 1) * 128 + rg * 64 + lane;
        for (;;) {
            unsigned int fv = llc_load4_wait(fp);
            if (__all(fv == 1u)) break;
            __builtin_amdgcn_s_sleep(8);
        }
    }
    __builtin_amdgcn_sched_barrier(0);

    unsigned short* As = lds;           // [2][4096] us
    unsigned short* Bs = lds + 8192;    // [2][4096] us

    const int srow = lane >> 2;
    const int scol = (lane & 3) * 8;
    const unsigned short *pA[2], *pB[2];
    unsigned short *lA[2], *lB[2];
    #pragma unroll
    for (int i = 0; i < 2; ++i) {
        int seg = wave * 2 + i;
        int row = seg * 16 + srow;                       // 0..127
        size_t ar = (size_t)(t + 1) * 16384 + rg * 128 + row;
        pA[i] = hs + (ar << 4) + ((scol >> 4) << 12) + (scol & 8);
        pB[i] = Wout + (size_t)(n * 128 + row) * 1024 + scol;
        lA[i] = As + seg * 512;
        lB[i] = Bs + seg * 512;
    }

    f32x4 acc[4][4] = {};
    const int foff = (lane & 15) * 32 + (lane >> 4) * 8;
    const int wrow0 = (wave >> 1) * 64, wcol0 = (wave & 1) * 64;

    #define G_STAGE(buf, k0)                                                  \
        GLOAD_LDS(pA[0] + (size_t)(k0) * 256, lA[0] + (buf) * 4096);          \
        GLOAD_LDS(pA[1] + (size_t)(k0) * 256, lA[1] + (buf) * 4096);          \
        GLOAD_LDS(pB[0] + (k0), lB[0] + (buf) * 4096);                        \
        GLOAD_LDS(pB[1] + (k0), lB[1] + (buf) * 4096);

    G_STAGE(0, 0)
    asm volatile("s_waitcnt vmcnt(0)" ::: "memory");
    __syncthreads();

    int cur = 0;
    for (int k0 = 0; k0 < 1024; k0 += 32) {
        if (k0 + 32 < 1024) { G_STAGE(cur ^ 1, k0 + 32) }

        bf16x8 a[4], b[4];
        #pragma unroll
        for (int mm = 0; mm < 4; ++mm)
            a[mm] = *(const bf16x8*)&As[cur * 4096 + (wrow0 + mm * 16) * 32 + foff];
        #pragma unroll
        for (int nn = 0; nn < 4; ++nn)
            b[nn] = *(const bf16x8*)&Bs[cur * 4096 + (wcol0 + nn * 16) * 32 + foff];
        #pragma unroll
        for (int mm = 0; mm < 4; ++mm)
            #pragma unroll
            for (int nn = 0; nn < 4; ++nn)
                acc[mm][nn] = __builtin_amdgcn_mfma_f32_16x16x32_bf16(
                    a[mm], b[nn], acc[mm][nn], 0, 0, 0);

        asm volatile("s_waitcnt vmcnt(0)" ::: "memory");
        __syncthreads();
        cur ^= 1;
    }
    #undef G_STAGE

    #pragma unroll
    for (int mm = 0; mm < 4; ++mm)
        #pragma unroll
        for (int j = 0; j < 4; ++j) {
            int rl = wrow0 + mm * 16 + (lane >> 4) * 4 + j;   // 0..127
            int bb = rg * 128 + rl;
            float* orow = out + (size_t)(bb * 40 + t) * 5000;
            #pragma unroll
            for (int nn = 0; nn < 4; ++nn) {
                int col = n * 128 + wcol0 + nn * 16 + (lane & 15);
                if (col < V_)
                    orow[col] = acc[mm][nn][j] + b_out[col];
            }
        }
}

// ---------------------------------------------------------------------------
// gates GEMM: gates[t][b][hc][q] (bf16, embedded in d_out rows b*40+t)
//   = gather(emb)[r=t*256+b] @ WihE(worig = (c&3)*1024 + c>>2)^T + baseMat
// 128x128 tile, 2-phase, K=512. Grid (32, 80).
// ---------------------------------------------------------------------------
__global__ __launch_bounds__(256) void gemm_gates(
    const unsigned short* __restrict__ A,      // emb_bf [V+1][512]
    const int* __restrict__ gidx,              // idxEmb [10240]
    const unsigned short* __restrict__ Bm,     // WihE_bf [4096][512]
    const float* __restrict__ baseMat,         // [256][4096] permuted
    unsigned short* __restrict__ gout)         // us view of d_out
{
    __shared__ unsigned short As[2][128 * 32];
    __shared__ unsigned short Bs[2][128 * 32];

    const int tid = threadIdx.x;
    const int wave = tid >> 6, lane = tid & 63;
    const int brow0 = blockIdx.y * 128, bcol0 = blockIdx.x * 128;
    const int wrow0 = (wave >> 1) * 64, wcol0 = (wave & 1) * 64;
    const int srow = lane >> 2, scol = (lane & 3) * 8;

    const unsigned short *pA[2], *pB[2];
    unsigned short *lA[2], *lB[2];
    #pragma unroll
    for (int i = 0; i < 2; ++i) {
        int seg = wave * 2 + i;
        int row = seg * 16 + srow;
        long long ar = gidx[brow0 + row];
        pA[i] = A + (size_t)ar * E_ + scol;
        int bc = bcol0 + row;
        pB[i] = Bm + (size_t)(((bc & 3) << 10) | (bc >> 2)) * E_ + scol;
        lA[i] = &As[0][seg * 512];
        lB[i] = &Bs[0][seg * 512];
    }

    f32x4 acc[4][4] = {};
    const int foff = (lane & 15) * 32 + (lane >> 4) * 8;

    #define STAGE(buf, k0)                                                    \
        GLOAD_LDS(pA[0] + (k0), lA[0] + (buf) * 4096);                        \
        GLOAD_LDS(pA[1] + (k0), lA[1] + (buf) * 4096);                        \
        GLOAD_LDS(pB[0] + (k0), lB[0] + (buf) * 4096);                        \
        GLOAD_LDS(pB[1] + (k0), lB[1] + (buf) * 4096);

    STAGE(0, 0)
    asm volatile("s_waitcnt vmcnt(0)" ::: "memory");
    __syncthreads();

    int cur = 0;
    for (int k0 = 0; k0 < E_; k0 += 32) {
        if (k0 + 32 < E_) { STAGE(cur ^ 1, k0 + 32) }

        bf16x8 a[4], b[4];
        #pragma unroll
        for (int mm = 0; mm < 4; ++mm)
            a[mm] = *(const bf16x8*)&As[0][cur * 4096 + (wrow0 + mm * 16) * 32 + foff];
        #pragma unroll
        for (int nn = 0; nn < 4; ++nn)
            b[nn] = *(const bf16x8*)&Bs[0][cur * 4096 + (wcol0 + nn * 16) * 32 + foff];
        #pragma unroll
        for (int mm = 0; mm < 4; ++mm)
            #pragma unroll
            for (int nn = 0; nn < 4; ++nn)
                acc[mm][nn] = __builtin_amdgcn_mfma_f32_16x16x32_bf16(
                    a[mm], b[nn], acc[mm][nn], 0, 0, 0);

        asm volatile("s_waitcnt vmcnt(0)" ::: "memory");
        __syncthreads();
        cur ^= 1;
    }
    #undef STAGE

    #pragma unroll
    for (int mm = 0; mm < 4; ++mm)
        #pragma unroll
        for (int j = 0; j < 4; ++j) {
            int row = brow0 + wrow0 + mm * 16 + (lane >> 4) * 4 + j; // t*256+b
            const float* addRow = baseMat + (size_t)(row & 255) * G4_;
            unsigned short* orow = gout +
                (size_t)((row & 255) * 40 + (row >> 8)) * 10000;
            #pragma unroll
            for (int nn = 0; nn < 4; ++nn) {
                int col = bcol0 + wcol0 + nn * 16 + (lane & 15);
                orow[col] = f2b(acc[mm][nn][j] + addRow[col]);
            }
        }
}

// ---------------------------------------------------------------------------
// fp32 tiled GEMM (two small GEMMs): C = A @ B^T + bias, optional permuted
// column store: col j -> ((j&1023)<<2) | (j>>10)   (for baseMat).
// ---------------------------------------------------------------------------
__global__ __launch_bounds__(256) void gemm_bt(
    const float* __restrict__ A, int lda,
    const float* __restrict__ Bm, int ldb,
    const float* __restrict__ bias,
    float* __restrict__ C, int ldc, int permuteC, int N, int K)
{
    const int BK = 16;
    __shared__ float As[BK][64];
    __shared__ float Bs[BK][64];

    const int tx = threadIdx.x, ty = threadIdx.y;
    const int tid = ty * 16 + tx;
    const int brow0 = blockIdx.y * 64;
    const int bcol0 = blockIdx.x * 64;

    const int e0   = tid * 4;
    const int la_r = e0 / BK;
    const int la_k = e0 % BK;

    const long long arow_base = (long long)(brow0 + la_r) * lda;
    const int bRowG = bcol0 + la_r;
    const bool bValid = (bRowG < N);
    const long long brow_base = (long long)bRowG * ldb;

    float acc[4][4] = {};

    for (int k0 = 0; k0 < K; k0 += BK) {
        float4 av = *(const float4*)(A + arow_base + k0 + la_k);
        float4 bv = make_float4(0.f, 0.f, 0.f, 0.f);
        if (bValid) bv = *(const float4*)(Bm + brow_base + k0 + la_k);

        As[la_k + 0][la_r] = av.x; As[la_k + 1][la_r] = av.y;
        As[la_k + 2][la_r] = av.z; As[la_k + 3][la_r] = av.w;
        Bs[la_k + 0][la_r] = bv.x; Bs[la_k + 1][la_r] = bv.y;
        Bs[la_k + 2][la_r] = bv.z; Bs[la_k + 3][la_r] = bv.w;
        __syncthreads();

        #pragma unroll
        for (int kk = 0; kk < BK; ++kk) {
            float af[4], bf[4];
            #pragma unroll
            for (int i = 0; i < 4; ++i) af[i] = As[kk][ty * 4 + i];
            #pragma unroll
            for (int j = 0; j < 4; ++j) bf[j] = Bs[kk][tx * 4 + j];
            #pragma unroll
            for (int i = 0; i < 4; ++i)
                #pragma unroll
                for (int j = 0; j < 4; ++j)
                    acc[i][j] = fmaf(af[i], bf[j], acc[i][j]);
        }
        __syncthreads();
    }

    #pragma unroll
    for (int i = 0; i < 4; ++i) {
        const int row = brow0 + ty * 4 + i;
        #pragma unroll
        for (int j = 0; j < 4; ++j) {
            const int col = bcol0 + tx * 4 + j;
            if (col < N) {
                float v = acc[i][j];
                if (bias) v += bias[col];
                int cidx = permuteC ? (((col & 1023) << 2) | (col >> 10)) : col;
                C[(long long)row * ldc + cidx] = v;
            }
        }
    }
}

// ---------------------------------------------------------------------------
// f32 -> bf16 conversion with optional column slice + zero row padding
// ---------------------------------------------------------------------------
__global__ void conv2bf(const float* __restrict__ src, unsigned short* __restrict__ dst,
                        int rows, int rowsPad, int cols, int srcld, int srccol0)
{
    int i = blockIdx.x * blockDim.x + threadIdx.x;
    int c4n = cols >> 2;
    if (i >= rowsPad * c4n) return;
    int r = i / c4n, c4 = i % c4n;
    ushort4 o;
    if (r < rows) {
        float4 v = *(const float4*)(src + (long long)r * srcld + srccol0 + c4 * 4);
        o.x = f2b(v.x); o.y = f2b(v.y); o.z = f2b(v.z); o.w = f2b(v.w);
    } else {
        o = make_ushort4(0, 0, 0, 0);
    }
    *(ushort4*)(dst + (long long)r * cols + c4 * 4) = o;
}

// ---------------------------------------------------------------------------
// prep: embedding gather indices (gates rows r = t*B + b) + combined bias
// ---------------------------------------------------------------------------
__global__ void prep_kernel(const int* __restrict__ labels,
                            const float* __restrict__ b_ih,
                            const float* __restrict__ b_hh,
                            int* __restrict__ idxEmb,
                            float* __restrict__ bsum)
{
    int r = blockIdx.x * blockDim.x + threadIdx.x;
    if (r < B_ * T_) {
        int t = r >> 8, b = r & (B_ - 1);
        int tsrc = (t == 0) ? (T_ - 1) : (t - 1);
        idxEmb[r] = labels[b * T_ + tsrc];
    }
    if (r < G4_) bsum[r] = b_ih[r] + b_hh[r];
}

extern "C" void kernel_launch(void* const* d_in, const int* in_sizes, int n_in,
                              void* d_out, int out_size, void* d_ws, size_t ws_size,
                              hipStream_t stream)
{
    const float* X      = (const float*)d_in[0];
    const int*   labels = (const int*)  d_in[1];
    const float* W_f    = (const float*)d_in[2];
    const float* b_f    = (const float*)d_in[3];
    const float* emb    = (const float*)d_in[4];
    const float* W_ih   = (const float*)d_in[5];
    const float* W_hh   = (const float*)d_in[6];
    const float* b_ih   = (const float*)d_in[7];
    const float* b_hh   = (const float*)d_in[8];
    const float* W_out  = (const float*)d_in[9];
    const float* b_out  = (const float*)d_in[10];
    float* out = (float*)d_out;
    (void)in_sizes; (void)n_in; (void)out_size; (void)ws_size;

    char* ws = (char*)d_ws;
    size_t off = 0;
    auto alloc = [&](size_t bytes) {
        void* p = ws + off;
        off += (bytes + 255) & ~(size_t)255;
        return p;
    };
    unsigned short* emb_bf  = (unsigned short*)alloc((size_t)(V_ + 1) * E_ * 2);
    unsigned short* WihE_bf = (unsigned short*)alloc((size_t)G4_ * E_ * 2);
    unsigned short* Whh_bf  = (unsigned short*)alloc((size_t)G4_ * H_ * 2);
    unsigned short* Wout_bf = (unsigned short*)alloc((size_t)5120 * H_ * 2);
    unsigned short* hs_bf   = (unsigned short*)alloc((size_t)(T_ + 1) * 262144 * 2);
    float* features = (float*)alloc(B_ * E_ * 4);
    float* baseMat  = (float*)alloc((size_t)B_ * G4_ * 4);
    float* bsum     = (float*)alloc(G4_ * 4);
    int*   idxEmb   = (int*)  alloc(B_ * T_ * 4);
    unsigned int* flags = (unsigned int*)alloc((size_t)(T_ + 1) * 128 * 4);

    // gates bf16 quads live INSIDE d_out: gates[t][b] = 8 KB at us-offset
    // (b*40+t)*10000 (out row b*40+t). Clobbered only by the logits tile
    // for t, which starts strictly after recurrence step t completes.
    unsigned short* gates_us = (unsigned short*)out;

    hipMemsetAsync(flags, 0, (size_t)(T_ + 1) * 128 * 4, stream);

    prep_kernel<<<(B_ * T_ + 255) / 256, 256, 0, stream>>>(
        labels, b_ih, b_hh, idxEmb, bsum);

    {
        int n;
        n = (V_ + 1) * E_ / 4;
        conv2bf<<<(n + 255) / 256, 256, 0, stream>>>(emb, emb_bf, V_ + 1, V_ + 1, E_, E_, 0);
        n = G4_ * E_ / 4;
        conv2bf<<<(n + 255) / 256, 256, 0, stream>>>(W_ih, WihE_bf, G4_, G4_, E_, 2 * E_, E_);
        n = G4_ * H_ / 4;
        conv2bf<<<(n + 255) / 256, 256, 0, stream>>>(W_hh, Whh_bf, G4_, G4_, H_, H_, 0);
        n = 5120 * H_ / 4;
        conv2bf<<<(n + 255) / 256, 256, 0, stream>>>(W_out, Wout_bf, V_, 5120, H_, H_, 0);
    }

    dim3 thr(16, 16);

    // features = X @ W_f^T + b_f            [256,512] K=2048 (fp32)
    gemm_bt<<<dim3(E_ / 64, B_ / 64), thr, 0, stream>>>(
        X, IN_, W_f, IN_, b_f, features, E_, 0, E_, IN_);

    // baseMat (PERMUTED cols) = features @ W_ih[:, :E]^T + (b_ih + b_hh)
    gemm_bt<<<dim3(G4_ / 64, B_ / 64), thr, 0, stream>>>(
        features, E_, W_ih, 2 * E_, bsum, baseMat, G4_, 1, G4_, E_);

    // gates (bf16 quads, scattered into d_out rows) = emb-gather GEMM
    gemm_gates<<<dim3(G4_ / 128, (B_ * T_) / 128), 256, 0, stream>>>(
        emb_bf, idxEmb, WihE_bf, baseMat, gates_us);

    // ---- mega: recurrence (128 CUs) overlapped with logits (128 CUs) ----
    {
        hipFuncSetAttribute((const void*)mega,
                            hipFuncAttributeMaxDynamicSharedMemorySize, 137216);
        mega<<<3328, 256, 137216, stream>>>(
            hs_bf, Whh_bf, gates_us, flags, Wout_bf, b_out, out);
    }
}

// Round 12
// 718.611 us; speedup vs baseline: 1.2861x; 1.2861x over previous
//
#include <hip/hip_runtime.h>
#include <hip/hip_bf16.h>
#include <math.h>

#define B_  256
#define T_  40
#define IN_ 2048
#define E_  512
#define H_  1024
#define V_  5000
#define G4_ 4096   // 4*H

typedef __bf16 bf16x8 __attribute__((ext_vector_type(8)));
typedef float  f32x4  __attribute__((ext_vector_type(4)));
typedef unsigned int u32x4 __attribute__((ext_vector_type(4)));

__device__ __forceinline__ float sigm_f(float x) { return 1.0f / (1.0f + __expf(-x)); }
__device__ __forceinline__ float tanh_f(float x) { return 1.0f - 2.0f / (1.0f + __expf(2.0f * x)); }

__device__ __forceinline__ unsigned short f2b(float x) {
    __hip_bfloat16 h = __float2bfloat16(x);
    return *reinterpret_cast<unsigned short*>(&h);
}
__device__ __forceinline__ float b2f(unsigned short u) {
    unsigned int v = (unsigned int)u << 16;
    return __builtin_bit_cast(float, v);
}

#define GLOAD_LDS(g, l) __builtin_amdgcn_global_load_lds(                     \
    (const __attribute__((address_space(1))) unsigned int*)(g),               \
    (__attribute__((address_space(3))) unsigned int*)(l), 16, 0, 0)

// normal (L2-cached) 16B load, manual vmcnt accounting via VM_WAIT
__device__ __forceinline__ void l2_load16(u32x4* dst, const unsigned short* p) {
    asm volatile("global_load_dwordx4 %0, %1, off" : "=v"(*dst) : "v"(p));
}
// LLC-coherent (cross-XCD) stores + poll
__device__ __forceinline__ void llc_store16(unsigned short* p, u32x4 v) {
    asm volatile("global_store_dwordx4 %0, %1, off sc0 sc1" :: "v"(p), "v"(v) : "memory");
}
__device__ __forceinline__ void llc_store4(unsigned int* p, unsigned int v) {
    asm volatile("global_store_dword %0, %1, off sc0 sc1" :: "v"(p), "v"(v) : "memory");
}
// poll load: waitcnt INSIDE the asm (compiler doesn't track asm loads)
__device__ __forceinline__ unsigned int llc_load4_wait(const unsigned int* p) {
    unsigned int v;
    asm volatile("global_load_dword %0, %1, off sc0 sc1\n\ts_waitcnt vmcnt(0)"
                 : "=v"(v) : "v"(p) : "memory");
    return v;
}
#define VM_WAIT(n) do {                                                       \
    asm volatile("s_waitcnt vmcnt(" #n ")" ::: "memory");                     \
    __builtin_amdgcn_sched_barrier(0);                                        \
} while (0)

// ---------------------------------------------------------------------------
// bf16 MFMA GEMM, depth-2 counted-vmcnt pipeline (3 LDS buffers, one raw
// barrier per K-iter; loads get 2 compute phases to land — no vmcnt(0) drain).
// C = gather(A) @ Bsel^T (+ bias) (+ addMat[(row&rowMask)*addStride + col])
// aBlocked: A stored as [kblk][256 rows][16] blocks (hs layout).
// bMapQ:    B row for (permuted) col c is (c&3)*1024 + (c>>2).
// OUTMODE 0: f32 store (bias/addMat in epilogue), col guarded by N.
// OUTMODE 1: bf16 store via LDS-staged coalesced 16B writes (requires
//            N % 128 == 0; addMat applied; bias ignored).
// 128x128 tile, BK=32, 256 thr = 4 waves, 16x16x32 MFMA. LDS 48 KB static.
// ---------------------------------------------------------------------------
template<int OUTMODE>
__global__ __launch_bounds__(256) void gemm_mfma(
    const unsigned short* __restrict__ A, int lda, int aBlocked,
    const int* __restrict__ gidx,
    const unsigned short* __restrict__ Bm, int ldb, int bMapQ,
    const float* __restrict__ bias,
    const float* __restrict__ addMat, int rowMask, long long addStride,
    void* __restrict__ Cout, int ldc, int N, int K)
{
    __shared__ unsigned short SH[24576];   // A bufs [3][4096] | B bufs [3][4096]

    const int tid  = threadIdx.x;
    const int wave = tid >> 6, lane = tid & 63;
    const int brow0 = blockIdx.y * 128, bcol0 = blockIdx.x * 128;
    const int wrow0 = (wave >> 1) * 64, wcol0 = (wave & 1) * 64;

    const int srow = lane >> 2;
    const int scol = (lane & 3) * 8;
    const size_t kstep = aBlocked ? 256 : 1;
    const unsigned short *pA[2], *pB[2];
    int segoff[2];
    #pragma unroll
    for (int i = 0; i < 2; ++i) {
        int seg = wave * 2 + i;
        int row = seg * 16 + srow;
        long long ar = gidx ? (long long)gidx[brow0 + row] : (long long)(brow0 + row);
        if (aBlocked)
            pA[i] = A + ((size_t)ar << 4) + ((size_t)(scol >> 4) << 12) + (scol & 8);
        else
            pA[i] = A + (size_t)ar * lda + scol;
        int bc = bcol0 + row;
        long long wrow = bMapQ ? (long long)(((bc & 3) << 10) | (bc >> 2)) : bc;
        pB[i] = Bm + wrow * ldb + scol;
        segoff[i] = seg * 512;
    }

    f32x4 acc[4][4] = {};
    const int foff = (lane & 15) * 32 + (lane >> 4) * 8;

    #define STAGE(buf, k0)                                                    \
        GLOAD_LDS(pA[0] + (size_t)(k0) * kstep, SH + (buf) * 4096 + segoff[0]); \
        GLOAD_LDS(pA[1] + (size_t)(k0) * kstep, SH + (buf) * 4096 + segoff[1]); \
        GLOAD_LDS(pB[0] + (k0), SH + 12288 + (buf) * 4096 + segoff[0]);       \
        GLOAD_LDS(pB[1] + (k0), SH + 12288 + (buf) * 4096 + segoff[1]);

    STAGE(0, 0)
    STAGE(1, 32)

    int cur = 0;
    for (int k0 = 0; k0 < K; k0 += 32) {
        if (k0 + 32 < K) { VM_WAIT(4); } else { VM_WAIT(0); }
        __builtin_amdgcn_s_barrier();   // raw: no implicit vmcnt(0) drain

        if (k0 + 64 < K) {
            int nb = cur + 2; if (nb >= 3) nb -= 3;
            STAGE(nb, k0 + 64)
        }

        bf16x8 a[4], b[4];
        #pragma unroll
        for (int m = 0; m < 4; ++m)
            a[m] = *(const bf16x8*)&SH[cur * 4096 + (wrow0 + m * 16) * 32 + foff];
        #pragma unroll
        for (int n = 0; n < 4; ++n)
            b[n] = *(const bf16x8*)&SH[12288 + cur * 4096 + (wcol0 + n * 16) * 32 + foff];
        #pragma unroll
        for (int m = 0; m < 4; ++m)
            #pragma unroll
            for (int n = 0; n < 4; ++n)
                acc[m][n] = __builtin_amdgcn_mfma_f32_16x16x32_bf16(
                    a[m], b[n], acc[m][n], 0, 0, 0);

        ++cur; if (cur == 3) cur = 0;
    }
    #undef STAGE

    if (OUTMODE == 0) {
        #pragma unroll
        for (int m = 0; m < 4; ++m)
            #pragma unroll
            for (int j = 0; j < 4; ++j) {
                int row = brow0 + wrow0 + m * 16 + (lane >> 4) * 4 + j;
                const float* addRow = addMat
                    ? addMat + (long long)(row & rowMask) * addStride : nullptr;
                #pragma unroll
                for (int n = 0; n < 4; ++n) {
                    int col = bcol0 + wcol0 + n * 16 + (lane & 15);
                    if (col < N) {
                        float v = acc[m][n][j];
                        if (addRow) v += addRow[col];
                        if (bias)   v += bias[col];
                        ((float*)Cout)[(long long)row * ldc + col] = v;
                    }
                }
            }
    } else {
        // LDS-staged bf16 epilogue: reuse SH[0..16384) as the C tile
        __syncthreads();
        #pragma unroll
        for (int m = 0; m < 4; ++m)
            #pragma unroll
            for (int j = 0; j < 4; ++j) {
                int lr = wrow0 + m * 16 + (lane >> 4) * 4 + j;
                int row = brow0 + lr;
                const float* addRow = addMat + (long long)(row & rowMask) * addStride;
                #pragma unroll
                for (int n = 0; n < 4; ++n) {
                    int lc = wcol0 + n * 16 + (lane & 15);
                    SH[lr * 128 + lc] = f2b(acc[m][n][j] + addRow[bcol0 + lc]);
                }
            }
        __syncthreads();
        #pragma unroll
        for (int p = 0; p < 8; ++p) {
            int idx = p * 256 + tid;
            int lr = idx >> 4, lc8 = (idx & 15) * 8;
            *(u32x4*)((unsigned short*)Cout + (size_t)(brow0 + lr) * ldc +
                      bcol0 + lc8) = *(const u32x4*)&SH[lr * 128 + lc8];
        }
    }
}

// ---------------------------------------------------------------------------
// Persistent LSTM recurrence (round-10 proven version, unchanged).
// 256 WGs x 256 thr. WG (mb,hb): batch rows mb*64..+64, h-cols hb*16..+16.
// W_hh slice LDS-resident 128 KB XOR-swizzled; gates bf16 quads [T][B][1024][4]
// prefetched one step ahead; h blocked [64 kblk][256 row][16]; per-wave flag
// sc0sc1 signaling + 64-lane parallel poll.
// ---------------------------------------------------------------------------
__global__ __launch_bounds__(256) void recur_persist(
    unsigned short* __restrict__ hs,          // slots 1..40, each 262144 elems
    const unsigned short* __restrict__ Whh,   // [4096,1024] bf16
    const unsigned short* __restrict__ gates, // [T,B,1024,4] bf16 (quad)
    unsigned int* __restrict__ flags)         // [(T+1)*256], zeroed
{
    extern __shared__ unsigned short lds[];   // [64][1024] bf16 = 128 KB
    __shared__ unsigned short hstage[64][24];

    const int tid = threadIdx.x;
    const int w = tid >> 6, lane = tid & 63;
    const int mb = blockIdx.x >> 6;
    const int hb = blockIdx.x & 63;
    const int r16 = lane & 15, g4 = lane >> 4;
    const int sw7 = r16 & 7;
    const size_t SLOT = 262144;

    const int arow = mb * 64 + w * 16 + r16;
    const size_t abase = ((size_t)arow << 4) + ((g4 >> 1) << 12) + ((g4 & 1) << 3);
    const int orow0 = mb * 64 + w * 16 + g4 * 4;
    const int hc    = hb * 16 + r16;
    const int lrow0 = w * 16 + g4 * 4;
    const size_t gq_base = ((size_t)orow0 << 12) + ((size_t)hc << 2);

    ushort4 gqc[4], gqn[4];
    #pragma unroll
    for (int j = 0; j < 4; ++j)
        gqc[j] = *(const ushort4*)(gates + gq_base + ((size_t)j << 12));

    {
        const int q = w;
        for (int r = 0; r < 16; ++r) {
            const int g = q * 16 + r;
            const unsigned short* rowsrc =
                Whh + ((size_t)q * 1024 + hb * 16 + r) * H_;
            #pragma unroll
            for (int half = 0; half < 2; ++half) {
                int gran = (half * 64 + lane) ^ (g & 7);
                GLOAD_LDS(rowsrc + gran * 8, &lds[g * 1024 + half * 512]);
            }
        }
    }
    asm volatile("s_waitcnt vmcnt(0)" ::: "memory");
    __syncthreads();

    int qbase[4];
    #pragma unroll
    for (int q = 0; q < 4; ++q) qbase[q] = (q * 16 + r16) << 11;

    float cc[4];

    #define STORE_H(T1, HV)                                                   \
    {                                                                         \
        _Pragma("unroll")                                                     \
        for (int j = 0; j < 4; ++j) hstage[lrow0 + j][r16] = HV[j];           \
        __syncthreads();                                                      \
        if (w == 0) {                                                         \
            unsigned short* dst0 = hs + (size_t)(T1) * SLOT +                 \
                (((size_t)hb * 256 + mb * 64) << 4);                          \
            _Pragma("unroll")                                                 \
            for (int s = 0; s < 2; ++s) {                                     \
                int idx = s * 64 + lane;                                      \
                u32x4 v = *(const u32x4*)&hstage[idx >> 1][(idx & 1) * 8];    \
                llc_store16(dst0 + (size_t)idx * 8, v);                       \
            }                                                                 \
            asm volatile("s_waitcnt vmcnt(0)" ::: "memory");                  \
            if (lane == 0)                                                    \
                llc_store4(flags + ((T1) << 8) + (mb << 6) + hb, 1u);         \
        }                                                                     \
    }

    // step 0
    {
        #pragma unroll
        for (int j = 0; j < 4; ++j)
            gqn[j] = *(const ushort4*)(gates + (1ull << 20) + gq_base +
                                       ((size_t)j << 12));
        unsigned short hv[4];
        #pragma unroll
        for (int j = 0; j < 4; ++j) {
            float gi = b2f(gqc[j].x), gg = b2f(gqc[j].z), go = b2f(gqc[j].w);
            float c2 = sigm_f(gi) * tanh_f(gg);
            cc[j] = c2;
            hv[j] = f2b(sigm_f(go) * tanh_f(c2));
        }
        STORE_H(1, hv)
        #pragma unroll
        for (int j = 0; j < 4; ++j) gqc[j] = gqn[j];
    }

    for (int t = 1; t < T_; ++t) {
        {
            const unsigned int* fp = flags + ((size_t)t << 8) + (mb << 6) + lane;
            for (;;) {
                unsigned int fv = llc_load4_wait(fp);
                if (__all(fv == 1u)) break;
                __builtin_amdgcn_s_sleep(1);
            }
        }
        __builtin_amdgcn_sched_barrier(0);

        const unsigned short* hp = hs + (size_t)t * SLOT + abase;

        u32x4 a0[8], a1[8];
        #pragma unroll
        for (int u = 0; u < 8; ++u) l2_load16(&a0[u], hp + (size_t)u * 8192);
        #pragma unroll
        for (int u = 0; u < 8; ++u) l2_load16(&a1[u], hp + (size_t)(8 + u) * 8192);

        f32x4 acc[4] = {};

#define DO_CHUNK(BUF, KSB)                                                    \
        _Pragma("unroll")                                                     \
        for (int u = 0; u < 8; ++u) {                                         \
            bf16x8 a8 = __builtin_bit_cast(bf16x8, BUF[u]);                   \
            _Pragma("unroll")                                                 \
            for (int q = 0; q < 4; ++q) {                                     \
                int off = qbase[q] + (((((KSB) + u) * 4 + g4) ^ sw7) << 4);   \
                bf16x8 b8 = *(const bf16x8*)((const char*)lds + off);         \
                acc[q] = __builtin_amdgcn_mfma_f32_16x16x32_bf16(             \
                    a8, b8, acc[q], 0, 0, 0);                                 \
            }                                                                 \
        }

        VM_WAIT(8);
        DO_CHUNK(a0, 0)
        #pragma unroll
        for (int u = 0; u < 8; ++u) l2_load16(&a0[u], hp + (size_t)(16 + u) * 8192);
        VM_WAIT(8);
        DO_CHUNK(a1, 8)
        #pragma unroll
        for (int u = 0; u < 8; ++u) l2_load16(&a1[u], hp + (size_t)(24 + u) * 8192);
        VM_WAIT(8);
        DO_CHUNK(a0, 16)
        VM_WAIT(0);
        DO_CHUNK(a1, 24)
#undef DO_CHUNK

        if (t + 1 < T_) {
            #pragma unroll
            for (int j = 0; j < 4; ++j)
                gqn[j] = *(const ushort4*)(gates +
                    ((size_t)(t + 1) << 20) + gq_base + ((size_t)j << 12));
        }

        unsigned short hv[4];
        #pragma unroll
        for (int j = 0; j < 4; ++j) {
            float gi = acc[0][j] + b2f(gqc[j].x);
            float gf = acc[1][j] + b2f(gqc[j].y);
            float gg = acc[2][j] + b2f(gqc[j].z);
            float go = acc[3][j] + b2f(gqc[j].w);
            float c2 = sigm_f(gf) * cc[j] + sigm_f(gi) * tanh_f(gg);
            cc[j] = c2;
            hv[j] = f2b(sigm_f(go) * tanh_f(c2));
        }
        STORE_H(t + 1, hv)
        #pragma unroll
        for (int j = 0; j < 4; ++j) gqc[j] = gqn[j];
    }
    #undef STORE_H
}

// ---------------------------------------------------------------------------
// fp32 tiled GEMM (features): C = A @ B^T + bias, optional bf16 store.
// ---------------------------------------------------------------------------
__global__ __launch_bounds__(256) void gemm_bt(
    const float* __restrict__ A, int lda,
    const float* __restrict__ Bm, int ldb,
    const float* __restrict__ bias,
    void* __restrict__ C, int ldc, int outBF16, int N, int K)
{
    const int BK = 16;
    __shared__ float As[BK][64];
    __shared__ float Bs[BK][64];

    const int tx = threadIdx.x, ty = threadIdx.y;
    const int tid = ty * 16 + tx;
    const int brow0 = blockIdx.y * 64;
    const int bcol0 = blockIdx.x * 64;

    const int e0   = tid * 4;
    const int la_r = e0 / BK;
    const int la_k = e0 % BK;

    const long long arow_base = (long long)(brow0 + la_r) * lda;
    const int bRowG = bcol0 + la_r;
    const bool bValid = (bRowG < N);
    const long long brow_base = (long long)bRowG * ldb;

    float acc[4][4] = {};

    for (int k0 = 0; k0 < K; k0 += BK) {
        float4 av = *(const float4*)(A + arow_base + k0 + la_k);
        float4 bv = make_float4(0.f, 0.f, 0.f, 0.f);
        if (bValid) bv = *(const float4*)(Bm + brow_base + k0 + la_k);

        As[la_k + 0][la_r] = av.x; As[la_k + 1][la_r] = av.y;
        As[la_k + 2][la_r] = av.z; As[la_k + 3][la_r] = av.w;
        Bs[la_k + 0][la_r] = bv.x; Bs[la_k + 1][la_r] = bv.y;
        Bs[la_k + 2][la_r] = bv.z; Bs[la_k + 3][la_r] = bv.w;
        __syncthreads();

        #pragma unroll
        for (int kk = 0; kk < BK; ++kk) {
            float af[4], bf[4];
            #pragma unroll
            for (int i = 0; i < 4; ++i) af[i] = As[kk][ty * 4 + i];
            #pragma unroll
            for (int j = 0; j < 4; ++j) bf[j] = Bs[kk][tx * 4 + j];
            #pragma unroll
            for (int i = 0; i < 4; ++i)
                #pragma unroll
                for (int j = 0; j < 4; ++j)
                    acc[i][j] = fmaf(af[i], bf[j], acc[i][j]);
        }
        __syncthreads();
    }

    #pragma unroll
    for (int i = 0; i < 4; ++i) {
        const int row = brow0 + ty * 4 + i;
        #pragma unroll
        for (int j = 0; j < 4; ++j) {
            const int col = bcol0 + tx * 4 + j;
            if (col < N) {
                float v = acc[i][j];
                if (bias) v += bias[col];
                if (outBF16)
                    ((unsigned short*)C)[(long long)row * ldc + col] = f2b(v);
                else
                    ((float*)C)[(long long)row * ldc + col] = v;
            }
        }
    }
}

// ---------------------------------------------------------------------------
// f32 -> bf16 conversion with optional column slice + zero row padding
// ---------------------------------------------------------------------------
__global__ void conv2bf(const float* __restrict__ src, unsigned short* __restrict__ dst,
                        int rows, int rowsPad, int cols, int srcld, int srccol0)
{
    int i = blockIdx.x * blockDim.x + threadIdx.x;
    int c4n = cols >> 2;
    if (i >= rowsPad * c4n) return;
    int r = i / c4n, c4 = i % c4n;
    ushort4 o;
    if (r < rows) {
        float4 v = *(const float4*)(src + (long long)r * srcld + srccol0 + c4 * 4);
        o.x = f2b(v.x); o.y = f2b(v.y); o.z = f2b(v.z); o.w = f2b(v.w);
    } else {
        o = make_ushort4(0, 0, 0, 0);
    }
    *(ushort4*)(dst + (long long)r * cols + c4 * 4) = o;
}

// ---------------------------------------------------------------------------
// prep: gather indices + PERMUTED combined bias
// idxEmb ordered for gates rows r = t*B + b
// idxLog: blocked-hs row index, ar = (t+1)*16384 + b  (rows r = b*T + t)
// bsum_perm[c] = b_ih[w] + b_hh[w],  w = (c&3)*1024 + (c>>2)
// ---------------------------------------------------------------------------
__global__ void prep_kernel(const int* __restrict__ labels,
                            const float* __restrict__ b_ih,
                            const float* __restrict__ b_hh,
                            int* __restrict__ idxEmb,
                            int* __restrict__ idxLog,
                            float* __restrict__ bsum_perm)
{
    int r = blockIdx.x * blockDim.x + threadIdx.x;
    if (r < B_ * T_) {
        {
            int t = r >> 8, b = r & (B_ - 1);
            int tsrc = (t == 0) ? (T_ - 1) : (t - 1);
            idxEmb[r] = labels[b * T_ + tsrc];
        }
        {
            int b = r / T_, t = r % T_;
            idxLog[r] = (t + 1) * 16384 + b;
        }
    }
    if (r < G4_) {
        int w = ((r & 3) << 10) | (r >> 2);
        bsum_perm[r] = b_ih[w] + b_hh[w];
    }
}

extern "C" void kernel_launch(void* const* d_in, const int* in_sizes, int n_in,
                              void* d_out, int out_size, void* d_ws, size_t ws_size,
                              hipStream_t stream)
{
    const float* X      = (const float*)d_in[0];
    const int*   labels = (const int*)  d_in[1];
    const float* W_f    = (const float*)d_in[2];
    const float* b_f    = (const float*)d_in[3];
    const float* emb    = (const float*)d_in[4];
    const float* W_ih   = (const float*)d_in[5];
    const float* W_hh   = (const float*)d_in[6];
    const float* b_ih   = (const float*)d_in[7];
    const float* b_hh   = (const float*)d_in[8];
    const float* W_out  = (const float*)d_in[9];
    const float* b_out  = (const float*)d_in[10];
    float* out = (float*)d_out;
    (void)in_sizes; (void)n_in; (void)out_size; (void)ws_size;

    char* ws = (char*)d_ws;
    size_t off = 0;
    auto alloc = [&](size_t bytes) {
        void* p = ws + off;
        off += (bytes + 255) & ~(size_t)255;
        return p;
    };
    unsigned short* emb_bf  = (unsigned short*)alloc((size_t)(V_ + 1) * E_ * 2);
    unsigned short* WihE_bf = (unsigned short*)alloc((size_t)G4_ * E_ * 2);
    unsigned short* WihA_bf = (unsigned short*)alloc((size_t)G4_ * E_ * 2);
    unsigned short* Whh_bf  = (unsigned short*)alloc((size_t)G4_ * H_ * 2);
    unsigned short* Wout_bf = (unsigned short*)alloc((size_t)5120 * H_ * 2);
    unsigned short* hs_bf   = (unsigned short*)alloc((size_t)(T_ + 1) * 262144 * 2);
    unsigned short* feat_bf = (unsigned short*)alloc((size_t)B_ * E_ * 2);
    float* bsum_perm = (float*)alloc(G4_ * 4);
    int*   idxEmb    = (int*)  alloc(B_ * T_ * 4);
    int*   idxLog    = (int*)  alloc(B_ * T_ * 4);
    unsigned int* flags = (unsigned int*)alloc((size_t)(T_ + 1) * 256 * 4);

    // d_out reuse: gates_bf [T,B,1024,4] bf16 (84 MB = 21M floats) at front,
    // consumed by the recurrence before the logits GEMM overwrites d_out;
    // baseMat (permuted-linear f32, 4 MB) in the tail.
    unsigned short* gates_bf = (unsigned short*)out;
    float* baseMat = out + 22 * 1024 * 1024;        // 22M + 1M < 51.2M floats

    hipMemsetAsync(flags, 0, (size_t)(T_ + 1) * 256 * 4, stream);

    prep_kernel<<<(B_ * T_ + 255) / 256, 256, 0, stream>>>(
        labels, b_ih, b_hh, idxEmb, idxLog, bsum_perm);

    {
        int n;
        n = (V_ + 1) * E_ / 4;
        conv2bf<<<(n + 255) / 256, 256, 0, stream>>>(emb, emb_bf, V_ + 1, V_ + 1, E_, E_, 0);
        n = G4_ * E_ / 4;
        conv2bf<<<(n + 255) / 256, 256, 0, stream>>>(W_ih, WihE_bf, G4_, G4_, E_, 2 * E_, E_);
        conv2bf<<<(n + 255) / 256, 256, 0, stream>>>(W_ih, WihA_bf, G4_, G4_, E_, 2 * E_, 0);
        n = G4_ * H_ / 4;
        conv2bf<<<(n + 255) / 256, 256, 0, stream>>>(W_hh, Whh_bf, G4_, G4_, H_, H_, 0);
        n = 5120 * H_ / 4;
        conv2bf<<<(n + 255) / 256, 256, 0, stream>>>(W_out, Wout_bf, V_, 5120, H_, H_, 0);
    }

    dim3 thr(16, 16);

    // features (bf16) = X @ W_f^T + b_f     [256,512] K=2048 (fp32 compute)
    gemm_bt<<<dim3(E_ / 64, B_ / 64), thr, 0, stream>>>(
        X, IN_, W_f, IN_, b_f, feat_bf, E_, 1, E_, IN_);

    // baseMat (permuted-linear f32) = feat @ WihA(q-mapped)^T + bsum_perm
    gemm_mfma<0><<<dim3(G4_ / 128, B_ / 128), 256, 0, stream>>>(
        feat_bf, E_, 0, nullptr, WihA_bf, E_, 1, nullptr,
        bsum_perm, 0, 0, baseMat, G4_, G4_, E_);

    // gates_bf[t,b,hc,q] = gather(emb_bf) @ WihE(q-mapped)^T + baseMat[b]
    gemm_mfma<1><<<dim3(G4_ / 128, (B_ * T_) / 128), 256, 0, stream>>>(
        emb_bf, E_, 0, idxEmb, WihE_bf, E_, 1, nullptr,
        baseMat, B_ - 1, G4_, gates_bf, G4_, G4_, E_);

    // ---- persistent recurrence (all 40 steps, one plain launch) ----
    {
        hipFuncSetAttribute((const void*)recur_persist,
                            hipFuncAttributeMaxDynamicSharedMemorySize, 131072);
        recur_persist<<<256, 256, 131072, stream>>>(hs_bf, Whh_bf, gates_bf, flags);
    }

    // logits = gather(hs_bf blocked) @ W_out^T + b_out   [10240,5000] K=1024
    gemm_mfma<0><<<dim3(5120 / 128, (B_ * T_) / 128), 256, 0, stream>>>(
        hs_bf, 16, 1, idxLog, Wout_bf, H_, 0, b_out,
        nullptr, 0, 0, out, V_, V_, H_);
}